// Round 10
// baseline (404.758 us; speedup 1.0000x reference)
//
#include <hip/hip_runtime.h>

// ---------------------------------------------------------------------------
// PreferencePredictor: logits[m] over M=131072 candidates.
// Heavy op: l = llm @ Wl^T (M=131072, K=768, N=256) -> HBM-bound (403 MB).
// Attention over 2 ctx rows collapses to 4 sigmoid gates + rank-4 update with
// precomputed wsd/csd/base/delta (prep_all block 96).
// R9: ALL register streaming. Evidence R2-R8: every global_load_lds-staged
// pipeline plateaus ~17-31 GB/s/CU staging regardless of depth/occupancy ->
// LDS-DMA path has shallow per-CU concurrency; register path is deep (m13
// copy ubench, HK reg-staging). So: no LDS, no barriers in the K-loop.
// Col-split waves (R5 layout): wave w owns 64 rows x cols [w*64,w*64+64),
// acc[4][4]. A: 8x16B/lane/step global->reg (4 waves load identical A ->
// 1 HBM fill + L1 hits; 8KB step working set << 32KB L1). B: 4x16B from L2.
// Named double-buffers, static 12x2 unroll (rule #20), compiler inserts
// counted vmcnt automatically. 8 independent waves/CU = TLP latency hiding.
// ws float layout:
//   [0,256) u  [256,512) qv  [512,768) k0  [768,1024) k1
//   [1024,1280) v0  [1280,1536) v1
//   [1536,2560) wsd[4][256]  [2560,2816) base[256]
//   [2816,3840) delta[4][256]  [3840,3844) csd[4]
//   float idx 4096: Bs bf16 fragment order Bs[kk(24)][nt(16)][lane(64)][i(8)]
// ---------------------------------------------------------------------------

typedef float f32x4 __attribute__((ext_vector_type(4)));
typedef __bf16 bf16x8 __attribute__((ext_vector_type(8)));

__device__ __forceinline__ unsigned f2bf(float f) {
  unsigned u = __builtin_bit_cast(unsigned, f);
  u += 0x7fffu + ((u >> 16) & 1u);   // round-to-nearest-even
  return u >> 16;
}

// ---- prep: blocks 0..95 = Wl fp32->bf16 fragment swizzle; block 96 = all
// small projections (u,qv,k,v,wsd,csd,base,delta).  (97 x 256) --------------
__global__ void prep_all(const float* __restrict__ user, const float* __restrict__ query,
                         const float* __restrict__ Wu, const float* __restrict__ bu,
                         const float* __restrict__ Wq, const float* __restrict__ bq,
                         const float* __restrict__ Wl,
                         const float* __restrict__ ipw, const float* __restrict__ ipb,
                         const float* __restrict__ opw, const float* __restrict__ opb,
                         float* __restrict__ wf, unsigned int* __restrict__ Bs4) {
  const int t = threadIdx.x;
  if (blockIdx.x < 96) {
    const int tid = blockIdx.x * 256 + t;           // (kk*16+nt)*64+lane
    const int lane = tid & 63;
    const int ntk = tid >> 6;
    const int kk = ntk >> 4, nt = ntk & 15;
    const int k = kk * 32 + (lane >> 4) * 8;
    const int j = nt * 16 + (lane & 15);
    const float* src = Wl + (size_t)j * 768 + k;
    uint4 pk;
    pk.x = f2bf(src[0]) | (f2bf(src[1]) << 16);
    pk.y = f2bf(src[2]) | (f2bf(src[3]) << 16);
    pk.z = f2bf(src[4]) | (f2bf(src[5]) << 16);
    pk.w = f2bf(src[6]) | (f2bf(src[7]) << 16);
    ((uint4*)Bs4)[tid] = pk;
    return;
  }
  // ---- block 96: small chain ----
  __shared__ float sh[1536];  // [0,512) u|qv  [512,1536) k0|k1|v0|v1
  for (int o = t; o < 512; o += 256) {
    const int isq = o >> 8, j = o & 255;
    const float* Wrow = (isq ? Wq : Wu) + (size_t)j * 768;
    const float* vec = isq ? query : user;
    float p = 0.f;
    for (int d = 0; d < 768; ++d) p = fmaf(Wrow[d], vec[d], p);
    p += (isq ? bq[j] : bu[j]);
    sh[o] = p; wf[o] = p;
  }
  __syncthreads();
  for (int o = t; o < 1024; o += 256) {
    const int kv = o >> 9, cc = (o >> 8) & 1, j = o & 255;
    const int row = 256 + kv * 256 + j;             // Wk rows 256..511, Wv 512..767
    const float* Wrow = ipw + (size_t)row * 256;
    const float* ctx = sh + cc * 256;
    float p = 0.f;
    for (int d = 0; d < 256; ++d) p = fmaf(Wrow[d], ctx[d], p);
    p += ipb[row];
    sh[512 + o] = p; wf[512 + o] = p;
  }
  __syncthreads();
  #pragma unroll
  for (int h = 0; h < 4; ++h) {                     // wsd[h][t]
    float acc = 0.f;
    for (int d = 0; d < 64; ++d) {
      const float kd = sh[512 + h * 64 + d] - sh[768 + h * 64 + d];
      acc = fmaf(ipw[(size_t)(h * 64 + d) * 256 + t], kd, acc);
    }
    wf[1536 + h * 256 + t] = 0.125f * acc;
  }
  if (t < 4) {                                      // csd[t]
    float cs = 0.f;
    for (int d = 0; d < 64; ++d)
      cs = fmaf(ipb[t * 64 + d], sh[512 + t * 64 + d] - sh[768 + t * 64 + d], cs);
    wf[3840 + t] = 0.125f * cs;
  }
  const float* oprow = opw + (size_t)t * 256;       // base[t], delta[h][t]
  float bse = 0.f;
  for (int i = 0; i < 256; ++i) bse = fmaf(oprow[i], sh[1280 + i], bse);
  wf[2560 + t] = bse + opb[t];
  #pragma unroll
  for (int h = 0; h < 4; ++h) {
    float dl = 0.f;
    for (int d = 0; d < 64; ++d)
      dl = fmaf(oprow[h * 64 + d], sh[1024 + h * 64 + d] - sh[1280 + h * 64 + d], dl);
    wf[2816 + h * 256 + t] = dl;
  }
}

// ---- main: 64 rows/block, 4 col-split waves; barrier-free reg streaming ---
__global__ __launch_bounds__(256, 2) void fused_main(
    const float* __restrict__ llm, const float* __restrict__ bl,
    const float* __restrict__ Wo, const float* __restrict__ bo,
    const float* __restrict__ wf, float* __restrict__ out) {

  __shared__ float wsd_s[1024], delta_s[1024];
  __shared__ float base_s[256], woa_s[256], wo2_s[256], bl_s[256];
  __shared__ float csd_s[4];
  __shared__ float psd_p[1024];   // [4 waves][64 rows][4 heads]
  __shared__ float pr2_p[256];    // [4 waves][64 rows]
  __shared__ float a_s[64][4];
  __shared__ float r2_s[64];
  __shared__ float p2_s[4][64];

  const int t = threadIdx.x;
  const int w = t >> 6, l = t & 63, g = l >> 4, c = l & 15;
  const int m0 = blockIdx.x * 64;
  const char* BsB = (const char*)(wf + 4096);

  // epilogue tables can load up front (no LDS contention with K-loop)
  for (int i = t; i < 1024; i += 256) { wsd_s[i] = wf[1536 + i]; delta_s[i] = wf[2816 + i]; }
  base_s[t] = wf[2560 + t];
  woa_s[t] = Wo[t];
  wo2_s[t] = Wo[256 + t];
  bl_s[t] = bl[t];
  if (t < 4) csd_s[t] = wf[3840 + t];

  // A: lane covers rows m0 + rf*16 + c, k-bytes [kk*128 + g*32, +32)
  const float* Abase = llm + (size_t)(m0 + c) * 768 + g * 8;

  f32x4 acc[4][4];
  #pragma unroll
  for (int rf = 0; rf < 4; ++rf)
    #pragma unroll
    for (int cf = 0; cf < 4; ++cf) acc[rf][cf] = (f32x4){0.f, 0.f, 0.f, 0.f};

  auto loadAB = [&](float4 (&fa)[4], float4 (&fb)[4], uint4 (&bb)[4], int kk) {
    const char* gb = BsB + (size_t)kk * 16384 + (size_t)l * 16;
    #pragma unroll
    for (int cf = 0; cf < 4; ++cf)
      bb[cf] = *(const uint4*)(gb + (w * 4 + cf) * 1024);
    #pragma unroll
    for (int rf = 0; rf < 4; ++rf) {
      const float* ap = Abase + (size_t)rf * (16 * 768) + kk * 32;
      fa[rf] = *(const float4*)(ap);
      fb[rf] = *(const float4*)(ap + 4);
    }
  };

  auto compute = [&](float4 (&fa)[4], float4 (&fb)[4], uint4 (&bb)[4]) {
    #pragma unroll
    for (int rf = 0; rf < 4; ++rf) {
      bf16x8 afr;
      afr[0] = (__bf16)fa[rf].x; afr[1] = (__bf16)fa[rf].y;
      afr[2] = (__bf16)fa[rf].z; afr[3] = (__bf16)fa[rf].w;
      afr[4] = (__bf16)fb[rf].x; afr[5] = (__bf16)fb[rf].y;
      afr[6] = (__bf16)fb[rf].z; afr[7] = (__bf16)fb[rf].w;
      #pragma unroll
      for (int cf = 0; cf < 4; ++cf)
        acc[rf][cf] = __builtin_amdgcn_mfma_f32_16x16x32_bf16(
            afr, __builtin_bit_cast(bf16x8, bb[cf]), acc[rf][cf], 0, 0, 0);
    }
  };

  float4 fa0[4], fb0[4], fa1[4], fb1[4];
  uint4 b0[4], b1[4];
  loadAB(fa0, fb0, b0, 0);
  loadAB(fa1, fb1, b1, 1);

  #pragma unroll
  for (int it = 0; it < 12; ++it) {
    compute(fa0, fb0, b0);
    if (it < 11) loadAB(fa0, fb0, b0, it * 2 + 2);
    compute(fa1, fb1, b1);
    if (it < 11) loadAB(fa1, fb1, b1, it * 2 + 3);
  }

  __syncthreads();   // tables resident; begin cross-wave epilogue

  // Pass 1 (col-split): per-wave partial sdiff/relu-dot over its 64 cols,
  // 16-lane shuffle reduce, per-rf. C frag (rf,cf): row = rf*16 + g*4 + j,
  // col = w*64 + cf*16 + c.
  #pragma unroll
  for (int rf = 0; rf < 4; ++rf) {
    float psd[4][4] = {};
    float pr2[4] = {};
    #pragma unroll
    for (int cf = 0; cf < 4; ++cf) {
      const int col = w * 64 + cf * 16 + c;
      const float w0 = wsd_s[col], w1 = wsd_s[256 + col],
                  w2 = wsd_s[512 + col], w3 = wsd_s[768 + col];
      const float wo = wo2_s[col], bb2 = bl_s[col];
      #pragma unroll
      for (int j = 0; j < 4; ++j) {
        const float x = acc[rf][cf][j] + bb2;
        psd[j][0] = fmaf(x, w0, psd[j][0]);
        psd[j][1] = fmaf(x, w1, psd[j][1]);
        psd[j][2] = fmaf(x, w2, psd[j][2]);
        psd[j][3] = fmaf(x, w3, psd[j][3]);
        pr2[j] = fmaf(fmaxf(x, 0.f), wo, pr2[j]);
      }
    }
    #pragma unroll
    for (int off = 8; off; off >>= 1) {
      #pragma unroll
      for (int j = 0; j < 4; ++j) {
        #pragma unroll
        for (int h = 0; h < 4; ++h) psd[j][h] += __shfl_xor(psd[j][h], off);
        pr2[j] += __shfl_xor(pr2[j], off);
      }
    }
    if (c == 0) {
      #pragma unroll
      for (int j = 0; j < 4; ++j) {
        const int row = rf * 16 + g * 4 + j;
        #pragma unroll
        for (int h = 0; h < 4; ++h) psd_p[w * 256 + row * 4 + h] = psd[j][h];
        pr2_p[w * 64 + row] = pr2[j];
      }
    }
  }
  __syncthreads();

  // combine partials across 4 waves -> gates + r2
  if (t < 64) {
    #pragma unroll
    for (int h = 0; h < 4; ++h) {
      float sd = csd_s[h];
      #pragma unroll
      for (int ww = 0; ww < 4; ++ww) sd += psd_p[ww * 256 + t * 4 + h];
      a_s[t][h] = 1.f / (1.f + __expf(-sd));
    }
    float rr = 0.f;
    #pragma unroll
    for (int ww = 0; ww < 4; ++ww) rr += pr2_p[ww * 64 + t];
    r2_s[t] = rr;
  }
  __syncthreads();

  // Pass 2: attended reconstruction + relu-dot, 4 col-quarters x 64 rows.
  {
    const int r = t & 63, q = t >> 6;
    const float a0 = a_s[r][0], a1 = a_s[r][1], a2 = a_s[r][2], a3 = a_s[r][3];
    float p = 0.f;
    const int j0 = q * 64;
    #pragma unroll 4
    for (int j = j0; j < j0 + 64; ++j) {
      float att = base_s[j];
      att = fmaf(a0, delta_s[j], att);
      att = fmaf(a1, delta_s[256 + j], att);
      att = fmaf(a2, delta_s[512 + j], att);
      att = fmaf(a3, delta_s[768 + j], att);
      p = fmaf(fmaxf(att, 0.f), woa_s[j], p);
    }
    p2_s[q][r] = p;
  }
  __syncthreads();
  if (t < 64)
    out[m0 + t] = p2_s[0][t] + p2_s[1][t] + p2_s[2][t] + p2_s[3][t] + r2_s[t] + bo[0];
}

// ---------------------------------------------------------------------------
extern "C" void kernel_launch(void* const* d_in, const int* in_sizes, int n_in,
                              void* d_out, int out_size, void* d_ws, size_t ws_size,
                              hipStream_t stream) {
  const float* user  = (const float*)d_in[0];
  const float* query = (const float*)d_in[1];
  const float* llm   = (const float*)d_in[2];
  const float* Wu    = (const float*)d_in[3];
  const float* bu    = (const float*)d_in[4];
  const float* Wq    = (const float*)d_in[5];
  const float* bq    = (const float*)d_in[6];
  const float* Wl    = (const float*)d_in[7];
  const float* bl    = (const float*)d_in[8];
  const float* ipw   = (const float*)d_in[9];
  const float* ipb   = (const float*)d_in[10];
  const float* opw   = (const float*)d_in[11];
  const float* opb   = (const float*)d_in[12];
  const float* Wo    = (const float*)d_in[13];
  const float* bo    = (const float*)d_in[14];
  float* out = (float*)d_out;
  float* wf = (float*)d_ws;
  unsigned int* Bs4 = (unsigned int*)(wf + 4096);

  prep_all<<<97, 256, 0, stream>>>(user, query, Wu, bu, Wq, bq, Wl,
                                   ipw, ipb, opw, opb, wf, Bs4);
  fused_main<<<131072 / 64, 256, 0, stream>>>(llm, bl, Wo, bo, wf, out);
}

// Round 11
// 291.514 us; speedup vs baseline: 1.3885x; 1.3885x over previous
//
#include <hip/hip_runtime.h>

// ---------------------------------------------------------------------------
// PreferencePredictor: logits[m] over M=131072 candidates.
// Heavy op: l = llm @ Wl^T (M=131072, K=768, N=256) -> HBM-bound (403 MB).
// Attention over 2 ctx rows collapses to 4 sigmoid gates + rank-4 update with
// precomputed wsd/csd/base/delta (prep_all block 96).
// R10: cross-round invariant: barrier-synced staging steps cost ~2 us
// regardless of bytes/depth/compute (R2/R4/R7/m97). Lever = rows per step.
// 128-row blocks with only 4 waves (256 thr), col-split: wave w owns ALL 128
// rows x cols [w*64,w*64+64), acc[8][4] (128 AGPR). Ring-2 {A:16KB fp32 |
// B:16KB bf16-frag} = 64 KB LDS, 2 blocks/CU. R4-proven sync per step:
// stage(next) -> VMCNT(8) counted -> s_barrier -> compute -> s_barrier.
// A XOR-swizzled (row&7)<<4 via inverse-swizzled global source; B pre-swizzled
// to MFMA fragment order by prep_all blocks 0..95.
// ws float layout:
//   [0,256) u  [256,512) qv  [512,768) k0  [768,1024) k1
//   [1024,1280) v0  [1280,1536) v1
//   [1536,2560) wsd[4][256]  [2560,2816) base[256]
//   [2816,3840) delta[4][256]  [3840,3844) csd[4]
//   float idx 4096: Bs bf16 fragment order Bs[kk(24)][nt(16)][lane(64)][i(8)]
// ---------------------------------------------------------------------------

typedef float f32x4 __attribute__((ext_vector_type(4)));
typedef __bf16 bf16x8 __attribute__((ext_vector_type(8)));

#define VMCNT(n) asm volatile("s_waitcnt vmcnt(" #n ")" ::: "memory")

__device__ __forceinline__ unsigned f2bf(float f) {
  unsigned u = __builtin_bit_cast(unsigned, f);
  u += 0x7fffu + ((u >> 16) & 1u);   // round-to-nearest-even
  return u >> 16;
}

__device__ __forceinline__ void gl_lds16(const void* g, void* l) {
  __builtin_amdgcn_global_load_lds(
      (const __attribute__((address_space(1))) void*)g,
      (__attribute__((address_space(3))) void*)l, 16, 0, 0);
}

// ---- prep: blocks 0..95 = Wl fp32->bf16 fragment swizzle; block 96 = all
// small projections (u,qv,k,v,wsd,csd,base,delta).  (97 x 256) --------------
__global__ void prep_all(const float* __restrict__ user, const float* __restrict__ query,
                         const float* __restrict__ Wu, const float* __restrict__ bu,
                         const float* __restrict__ Wq, const float* __restrict__ bq,
                         const float* __restrict__ Wl,
                         const float* __restrict__ ipw, const float* __restrict__ ipb,
                         const float* __restrict__ opw, const float* __restrict__ opb,
                         float* __restrict__ wf, unsigned int* __restrict__ Bs4) {
  const int t = threadIdx.x;
  if (blockIdx.x < 96) {
    const int tid = blockIdx.x * 256 + t;           // (kk*16+nt)*64+lane
    const int lane = tid & 63;
    const int ntk = tid >> 6;
    const int kk = ntk >> 4, nt = ntk & 15;
    const int k = kk * 32 + (lane >> 4) * 8;
    const int j = nt * 16 + (lane & 15);
    const float* src = Wl + (size_t)j * 768 + k;
    uint4 pk;
    pk.x = f2bf(src[0]) | (f2bf(src[1]) << 16);
    pk.y = f2bf(src[2]) | (f2bf(src[3]) << 16);
    pk.z = f2bf(src[4]) | (f2bf(src[5]) << 16);
    pk.w = f2bf(src[6]) | (f2bf(src[7]) << 16);
    ((uint4*)Bs4)[tid] = pk;
    return;
  }
  // ---- block 96: small chain ----
  __shared__ float sh[1536];  // [0,512) u|qv  [512,1536) k0|k1|v0|v1
  for (int o = t; o < 512; o += 256) {
    const int isq = o >> 8, j = o & 255;
    const float* Wrow = (isq ? Wq : Wu) + (size_t)j * 768;
    const float* vec = isq ? query : user;
    float p = 0.f;
    for (int d = 0; d < 768; ++d) p = fmaf(Wrow[d], vec[d], p);
    p += (isq ? bq[j] : bu[j]);
    sh[o] = p; wf[o] = p;
  }
  __syncthreads();
  for (int o = t; o < 1024; o += 256) {
    const int kv = o >> 9, cc = (o >> 8) & 1, j = o & 255;
    const int row = 256 + kv * 256 + j;             // Wk rows 256..511, Wv 512..767
    const float* Wrow = ipw + (size_t)row * 256;
    const float* ctx = sh + cc * 256;
    float p = 0.f;
    for (int d = 0; d < 256; ++d) p = fmaf(Wrow[d], ctx[d], p);
    p += ipb[row];
    sh[512 + o] = p; wf[512 + o] = p;
  }
  __syncthreads();
  #pragma unroll
  for (int h = 0; h < 4; ++h) {                     // wsd[h][t]
    float acc = 0.f;
    for (int d = 0; d < 64; ++d) {
      const float kd = sh[512 + h * 64 + d] - sh[768 + h * 64 + d];
      acc = fmaf(ipw[(size_t)(h * 64 + d) * 256 + t], kd, acc);
    }
    wf[1536 + h * 256 + t] = 0.125f * acc;
  }
  if (t < 4) {                                      // csd[t]
    float cs = 0.f;
    for (int d = 0; d < 64; ++d)
      cs = fmaf(ipb[t * 64 + d], sh[512 + t * 64 + d] - sh[768 + t * 64 + d], cs);
    wf[3840 + t] = 0.125f * cs;
  }
  const float* oprow = opw + (size_t)t * 256;       // base[t], delta[h][t]
  float bse = 0.f;
  for (int i = 0; i < 256; ++i) bse = fmaf(oprow[i], sh[1280 + i], bse);
  wf[2560 + t] = bse + opb[t];
  #pragma unroll
  for (int h = 0; h < 4; ++h) {
    float dl = 0.f;
    for (int d = 0; d < 64; ++d)
      dl = fmaf(oprow[h * 64 + d], sh[1024 + h * 64 + d] - sh[1280 + h * 64 + d], dl);
    wf[2816 + h * 256 + t] = dl;
  }
}

// ---- main: 128 rows/block, 256 threads (4 col-split waves); ring-2 --------
// LDS (bytes): [0,32768) A ring[2][16384]  [32768,65536) B ring[2][16384]
// Epilogue overlay (floats from smem base):
//   [0,1024) wsd  [1024,2048) delta  [2048,2304) base  [2304,2560) woa
//   [2560,2816) wo2  [2816,3072) bl  [3072,5120) psd_p[4][128][4]
//   [5120,5632) pr2_p[4][128]  [5632,6144) a_s[128][4]  [6144,6272) r2_s[128]
//   [6272,6528) p2_s[2][128]  [6528,6532) csd_s[4]
__global__ __launch_bounds__(256, 2) void fused_main(
    const float* __restrict__ llm, const float* __restrict__ bl,
    const float* __restrict__ Wo, const float* __restrict__ bo,
    const float* __restrict__ wf, float* __restrict__ out) {

  __shared__ __align__(16) char smem[65536];

  const int t = threadIdx.x;
  const int w = t >> 6, l = t & 63, g = l >> 4, c = l & 15;
  const int m0 = blockIdx.x * 128;
  const char* BsB = (const char*)(wf + 4096);

  // stage pair {A(kk):16KB, B(kk):16KB} into ring slot: 8 gl_lds per wave.
  auto stage_pair = [&](int slot, int kk) {
    #pragma unroll
    for (int r = 0; r < 4; ++r) {
      const int chunk = r * 256 + w * 64 + l;        // 0..1023
      const int row = chunk >> 3;                    // 0..127
      const int cb = (chunk & 7) * 16;               // physical col-byte
      const int cl = cb ^ ((row & 7) << 4);          // inverse-swizzled source
      const char* gp = (const char*)(llm + (size_t)(m0 + row) * 768 + kk * 32) + cl;
      gl_lds16(gp, smem + slot * 16384 + r * 4096 + w * 1024);
    }
    const char* gb = BsB + (size_t)kk * 16384;
    #pragma unroll
    for (int r = 0; r < 4; ++r) {
      const int chunk = r * 256 + w * 64 + l;
      gl_lds16(gb + (size_t)chunk * 16,
               smem + 32768 + slot * 16384 + r * 4096 + w * 1024);
    }
  };

  stage_pair(0, 0);        // prologue: pair 0 in flight

  f32x4 acc[8][4];
  #pragma unroll
  for (int rf = 0; rf < 8; ++rf)
    #pragma unroll
    for (int cf = 0; cf < 4; ++cf) acc[rf][cf] = (f32x4){0.f, 0.f, 0.f, 0.f};

  const int sx = (c & 7) << 4;

  for (int kk = 0; kk < 24; ++kk) {
    if (kk < 23) { stage_pair((kk + 1) & 1, kk + 1); VMCNT(8); }
    else         { VMCNT(0); }
    __builtin_amdgcn_s_barrier();            // pair kk visible to all waves

    const char* ab = smem + (kk & 1) * 16384;
    const char* bb = smem + 32768 + (kk & 1) * 16384 + (size_t)(w * 4) * 1024 + l * 16;

    #pragma unroll
    for (int rf = 0; rf < 8; ++rf) {
      const int row = rf * 16 + c;
      const char* rp = ab + row * 128;
      const float4 fa = *(const float4*)(rp + ((g * 32) ^ sx));
      const float4 fb = *(const float4*)(rp + ((g * 32 + 16) ^ sx));
      uint4 pk;
      pk.x = f2bf(fa.x) | (f2bf(fa.y) << 16);
      pk.y = f2bf(fa.z) | (f2bf(fa.w) << 16);
      pk.z = f2bf(fb.x) | (f2bf(fb.y) << 16);
      pk.w = f2bf(fb.z) | (f2bf(fb.w) << 16);
      const bf16x8 afr = __builtin_bit_cast(bf16x8, pk);
      #pragma unroll
      for (int cf = 0; cf < 4; ++cf) {
        const bf16x8 bfr = *(const bf16x8*)(bb + cf * 1024);
        acc[rf][cf] = __builtin_amdgcn_mfma_f32_16x16x32_bf16(
            afr, bfr, acc[rf][cf], 0, 0, 0);
      }
    }
    __builtin_amdgcn_s_barrier();            // readers done before overwrite
  }

  __syncthreads();   // K-loop fully done before smem overlay

  // ---- epilogue overlay ----
  float* smf = (float*)smem;
  float* wsd_s  = smf;           // [1024]
  float* delta_s = smf + 1024;   // [1024]
  float* base_s = smf + 2048;    // [256]
  float* woa_s  = smf + 2304;    // [256]
  float* wo2_s  = smf + 2560;    // [256]
  float* bl_s   = smf + 2816;    // [256]
  float* psd_p  = smf + 3072;    // [4][128][4]
  float* pr2_p  = smf + 5120;    // [4][128]
  float* a_s    = smf + 5632;    // [128][4]
  float* r2_s   = smf + 6144;    // [128]
  float* p2_s   = smf + 6272;    // [2][128]
  float* csd_s  = smf + 6528;    // [4]
  for (int i = t; i < 1024; i += 256) { wsd_s[i] = wf[1536 + i]; delta_s[i] = wf[2816 + i]; }
  base_s[t] = wf[2560 + t];
  woa_s[t] = Wo[t];
  wo2_s[t] = Wo[256 + t];
  bl_s[t] = bl[t];
  if (t < 4) csd_s[t] = wf[3840 + t];
  __syncthreads();

  // Pass 1: per-wave partial sdiff[h]/relu-dot over its 64 cols, per rf;
  // 16-lane shuffle reduce. C frag (rf,cf): row = rf*16+g*4+j,
  // col = w*64+cf*16+c.
  #pragma unroll
  for (int rf = 0; rf < 8; ++rf) {
    float psd[4][4] = {};
    float pr2[4] = {};
    #pragma unroll
    for (int cf = 0; cf < 4; ++cf) {
      const int col = w * 64 + cf * 16 + c;
      const float w0 = wsd_s[col], w1 = wsd_s[256 + col],
                  w2 = wsd_s[512 + col], w3 = wsd_s[768 + col];
      const float wo = wo2_s[col], bb2 = bl_s[col];
      #pragma unroll
      for (int j = 0; j < 4; ++j) {
        const float x = acc[rf][cf][j] + bb2;
        psd[j][0] = fmaf(x, w0, psd[j][0]);
        psd[j][1] = fmaf(x, w1, psd[j][1]);
        psd[j][2] = fmaf(x, w2, psd[j][2]);
        psd[j][3] = fmaf(x, w3, psd[j][3]);
        pr2[j] = fmaf(fmaxf(x, 0.f), wo, pr2[j]);
      }
    }
    #pragma unroll
    for (int off = 8; off; off >>= 1) {
      #pragma unroll
      for (int j = 0; j < 4; ++j) {
        #pragma unroll
        for (int h = 0; h < 4; ++h) psd[j][h] += __shfl_xor(psd[j][h], off);
        pr2[j] += __shfl_xor(pr2[j], off);
      }
    }
    if (c == 0) {
      #pragma unroll
      for (int j = 0; j < 4; ++j) {
        const int row = rf * 16 + g * 4 + j;
        #pragma unroll
        for (int h = 0; h < 4; ++h) psd_p[w * 512 + row * 4 + h] = psd[j][h];
        pr2_p[w * 128 + row] = pr2[j];
      }
    }
  }
  __syncthreads();

  // combine partials across 4 waves -> gates + r2
  if (t < 128) {
    #pragma unroll
    for (int h = 0; h < 4; ++h) {
      float sd = csd_s[h];
      #pragma unroll
      for (int ww = 0; ww < 4; ++ww) sd += psd_p[ww * 512 + t * 4 + h];
      a_s[t * 4 + h] = 1.f / (1.f + __expf(-sd));
    }
    float rr = 0.f;
    #pragma unroll
    for (int ww = 0; ww < 4; ++ww) rr += pr2_p[ww * 128 + t];
    r2_s[t] = rr;
  }
  __syncthreads();

  // Pass 2: attended reconstruction + relu-dot, 2 col-halves x 128 rows.
  {
    const int r = t & 127, q = t >> 7;
    const float a0 = a_s[r * 4], a1 = a_s[r * 4 + 1],
                a2 = a_s[r * 4 + 2], a3 = a_s[r * 4 + 3];
    float p = 0.f;
    const int j0 = q * 128;
    #pragma unroll 4
    for (int j = j0; j < j0 + 128; ++j) {
      float att = base_s[j];
      att = fmaf(a0, delta_s[j], att);
      att = fmaf(a1, delta_s[256 + j], att);
      att = fmaf(a2, delta_s[512 + j], att);
      att = fmaf(a3, delta_s[768 + j], att);
      p = fmaf(fmaxf(att, 0.f), woa_s[j], p);
    }
    p2_s[q * 128 + r] = p;
  }
  __syncthreads();
  if (t < 128)
    out[m0 + t] = p2_s[t] + p2_s[128 + t] + r2_s[t] + bo[0];
}

// ---------------------------------------------------------------------------
extern "C" void kernel_launch(void* const* d_in, const int* in_sizes, int n_in,
                              void* d_out, int out_size, void* d_ws, size_t ws_size,
                              hipStream_t stream) {
  const float* user  = (const float*)d_in[0];
  const float* query = (const float*)d_in[1];
  const float* llm   = (const float*)d_in[2];
  const float* Wu    = (const float*)d_in[3];
  const float* bu    = (const float*)d_in[4];
  const float* Wq    = (const float*)d_in[5];
  const float* bq    = (const float*)d_in[6];
  const float* Wl    = (const float*)d_in[7];
  const float* bl    = (const float*)d_in[8];
  const float* ipw   = (const float*)d_in[9];
  const float* ipb   = (const float*)d_in[10];
  const float* opw   = (const float*)d_in[11];
  const float* opb   = (const float*)d_in[12];
  const float* Wo    = (const float*)d_in[13];
  const float* bo    = (const float*)d_in[14];
  float* out = (float*)d_out;
  float* wf = (float*)d_ws;
  unsigned int* Bs4 = (unsigned int*)(wf + 4096);

  prep_all<<<97, 256, 0, stream>>>(user, query, Wu, bu, Wq, bq, Wl,
                                   ipw, ipb, opw, opb, wf, Bs4);
  fused_main<<<131072 / 128, 256, 0, stream>>>(llm, bl, Wo, bo, wf, out);
}

// Round 12
// 203.940 us; speedup vs baseline: 1.9847x; 1.4294x over previous
//
#include <hip/hip_runtime.h>

// ---------------------------------------------------------------------------
// PreferencePredictor: logits[m] over M=131072 candidates.
// Heavy op: l = llm @ Wl^T (M=131072, K=768, N=256) -> HBM-bound (403 MB).
// Attention over 2 ctx rows collapses to 4 sigmoid gates + rank-4 update with
// precomputed wsd/csd/base/delta (prep kernels, SPLIT: merged prep_all's
// block-96 serial chain measured ~100us due to uncoalesced weight reads).
// R11: convoy-depth experiment. R4(3 blk/CU)=148us fused == R8(2 blk/CU,
// half the staged bytes) -> not byte-bound; barrier-convoy floor scales with
// concurrent blocks/CU. Target 4 blocks/CU:
//   - col-split waves (R5 layout): wave w owns 64 rows x cols [w*64,+64),
//     acc[4][4] = 64 VGPR.
//   - B: named-register double-buffer b[2][4] (32 VGPR), direct from L2,
//     zero redundancy, full 24-step unroll (static indices, rule #20).
//   - A: ring-2 LDS via global_load_lds (16 KB only), XOR swizzle (row&7)<<4
//     via inverse-swizzled global source.
//   - Per step: s_barrier + sched_barrier -> stageA(kk+1) + loadB(kk+1) ->
//     VMCNT(6) (retires tile kk's 6 ops, tile kk+1 stays in flight) ->
//     2 ds_read + pack + 16 MFMA. One barrier/step.
//   - __launch_bounds__(256,4): VGPR cap 128 -> 4 blocks/CU, 16 waves/CU.
// ws float layout:
//   [0,256) u  [256,512) qv  [512,768) k0  [768,1024) k1
//   [1024,1280) v0  [1280,1536) v1
//   [1536,2560) wsd[4][256]  [2560,2816) base[256]
//   [2816,3840) delta[4][256]  [3840,3844) csd[4]
//   float idx 4096: Bs bf16 fragment order Bs[kk(24)][nt(16)][lane(64)][i(8)]
// ---------------------------------------------------------------------------

typedef float f32x4 __attribute__((ext_vector_type(4)));
typedef __bf16 bf16x8 __attribute__((ext_vector_type(8)));

#define VMCNT(n) asm volatile("s_waitcnt vmcnt(" #n ")" ::: "memory")

__device__ __forceinline__ unsigned f2bf(float f) {
  unsigned u = __builtin_bit_cast(unsigned, f);
  u += 0x7fffu + ((u >> 16) & 1u);   // round-to-nearest-even
  return u >> 16;
}

__device__ __forceinline__ void gl_lds16(const void* g, void* l) {
  __builtin_amdgcn_global_load_lds(
      (const __attribute__((address_space(1))) void*)g,
      (__attribute__((address_space(3))) void*)l, 16, 0, 0);
}

// ---- prep_a: u = user@Wu^T+bu, qv = query@Wq^T+bq  (64 blocks x 256) ------
__global__ void prep_a(const float* __restrict__ user, const float* __restrict__ query,
                       const float* __restrict__ Wu, const float* __restrict__ bu,
                       const float* __restrict__ Wq, const float* __restrict__ bq,
                       float* __restrict__ wf) {
  const int og = threadIdx.x >> 5, ln = threadIdx.x & 31;
  const int o = blockIdx.x * 8 + og;        // 0..511
  const int isq = o >> 8, j = o & 255;
  const float* Wrow = (isq ? Wq : Wu) + (size_t)j * 768;
  const float* vec = isq ? query : user;
  float p = 0.f;
  #pragma unroll
  for (int i = 0; i < 24; ++i) { int d = ln * 24 + i; p = fmaf(Wrow[d], vec[d], p); }
  #pragma unroll
  for (int off = 16; off; off >>= 1) p += __shfl_xor(p, off);
  if (ln == 0) wf[o] = p + (isq ? bq[j] : bu[j]);
}

// ---- prep_b: k0,k1,v0,v1 from ctx={u,qv}  (128 blocks x 256) --------------
__global__ void prep_b(const float* __restrict__ ipw, const float* __restrict__ ipb,
                       float* __restrict__ wf) {
  const int og = threadIdx.x >> 5, ln = threadIdx.x & 31;
  const int o = blockIdx.x * 8 + og;        // 0..1023
  const int kv = o >> 9, cc = (o >> 8) & 1, j = o & 255;
  const int row = 256 + kv * 256 + j;
  const float* Wrow = ipw + (size_t)row * 256;
  const float* ctx = wf + cc * 256;
  float p = 0.f;
  #pragma unroll
  for (int i = 0; i < 8; ++i) { int d = ln * 8 + i; p = fmaf(Wrow[d], ctx[d], p); }
  #pragma unroll
  for (int off = 16; off; off >>= 1) p += __shfl_xor(p, off);
  if (ln == 0) wf[512 + o] = p + ipb[row];
}

// ---- prep_c: wsd, csd (blocks 0-3), base, delta (block 4)  (5 x 256) ------
__global__ void prep_c(const float* __restrict__ ipw, const float* __restrict__ ipb,
                       const float* __restrict__ opw, const float* __restrict__ opb,
                       float* __restrict__ wf) {
  const int t = threadIdx.x, b = blockIdx.x;
  if (b < 4) {
    const int h = b;
    float acc = 0.f;
    for (int d = 0; d < 64; ++d) {
      float kd = wf[512 + h * 64 + d] - wf[768 + h * 64 + d];
      acc = fmaf(ipw[(size_t)(h * 64 + d) * 256 + t], kd, acc);
    }
    wf[1536 + h * 256 + t] = 0.125f * acc;
    if (t == 0) {
      float cs = 0.f;
      for (int d = 0; d < 64; ++d)
        cs = fmaf(ipb[h * 64 + d], wf[512 + h * 64 + d] - wf[768 + h * 64 + d], cs);
      wf[3840 + h] = 0.125f * cs;
    }
  } else {
    const float* oprow = opw + (size_t)t * 256;
    float bse = 0.f;
    for (int i = 0; i < 256; ++i) bse = fmaf(oprow[i], wf[1280 + i], bse);
    wf[2560 + t] = bse + opb[t];
    #pragma unroll
    for (int h = 0; h < 4; ++h) {
      float dl = 0.f;
      for (int d = 0; d < 64; ++d)
        dl = fmaf(oprow[h * 64 + d], wf[1024 + h * 64 + d] - wf[1280 + h * 64 + d], dl);
      wf[2816 + h * 256 + t] = dl;
    }
  }
}

// ---- prep_w: Wl fp32 -> bf16, pre-swizzled B-fragment layout (96 x 256) ---
__global__ void prep_w(const float* __restrict__ Wl, unsigned int* __restrict__ Bs4) {
  const int tid = blockIdx.x * 256 + threadIdx.x;   // (kk*16+nt)*64+lane
  const int lane = tid & 63;
  const int ntk = tid >> 6;
  const int kk = ntk >> 4, nt = ntk & 15;
  const int k = kk * 32 + (lane >> 4) * 8;
  const int j = nt * 16 + (lane & 15);
  const float* src = Wl + (size_t)j * 768 + k;
  uint4 pk;
  pk.x = f2bf(src[0]) | (f2bf(src[1]) << 16);
  pk.y = f2bf(src[2]) | (f2bf(src[3]) << 16);
  pk.z = f2bf(src[4]) | (f2bf(src[5]) << 16);
  pk.w = f2bf(src[6]) | (f2bf(src[7]) << 16);
  ((uint4*)Bs4)[tid] = pk;
}

// ---- main: 64 rows/block, 4 col-split waves; A ring-2 + B reg-dbuf --------
__global__ __launch_bounds__(256, 4) void fused_main(
    const float* __restrict__ llm, const float* __restrict__ bl,
    const float* __restrict__ Wo, const float* __restrict__ bo,
    const float* __restrict__ wf, float* __restrict__ out) {

  __shared__ __align__(16) char smem[16384];   // A ring[2][8192]
  __shared__ float wsd_s[1024], delta_s[1024];
  __shared__ float base_s[256], woa_s[256], wo2_s[256], bl_s[256];
  __shared__ float csd_s[4];
  __shared__ float psd_p[1024];   // [4 waves][64 rows][4 heads]
  __shared__ float pr2_p[256];    // [4 waves][64 rows]
  __shared__ float a_s[64][4];
  __shared__ float r2_s[64];
  __shared__ float p2_s[4][64];

  const int t = threadIdx.x;
  const int w = t >> 6, l = t & 63, g = l >> 4, c = l & 15;
  const int m0 = blockIdx.x * 64;
  const char* BsB = (const char*)(wf + 4096);

  // stage A K-tile kk into ring slot: 8 KB via 2 gl_lds per wave.
  auto stageA = [&](int slot, int kk) {
    char* abase = smem + slot * 8192 + w * 1024;
    #pragma unroll
    for (int r = 0; r < 2; ++r) {
      const int chunk = r * 256 + w * 64 + l;        // 16B-chunk index
      const int row = chunk >> 3;                    // 0..63
      const int cb = (chunk & 7) * 16;               // physical col-byte
      const int cl = cb ^ ((row & 7) << 4);          // inverse-swizzled source
      const char* gp = (const char*)(llm + (size_t)(m0 + row) * 768 + kk * 32) + cl;
      gl_lds16(gp, abase + r * 4096);
    }
  };
  // B fragments for K-tile kk into register slot (4x 16B loads, L2-resident).
  auto loadB = [&](uint4* dst, int kk) {
    const char* gb = BsB + (size_t)kk * 16384 + (size_t)l * 16;
    #pragma unroll
    for (int cf = 0; cf < 4; ++cf)
      dst[cf] = *(const uint4*)(gb + (w * 4 + cf) * 1024);
  };

  uint4 b[2][4];
  stageA(0, 0);        // prologue: tile 0 pair in flight (6 ops)
  loadB(b[0], 0);

  f32x4 acc[4][4];
  #pragma unroll
  for (int rf = 0; rf < 4; ++rf)
    #pragma unroll
    for (int cf = 0; cf < 4; ++cf) acc[rf][cf] = (f32x4){0.f, 0.f, 0.f, 0.f};

  const int sx = (c & 7) << 4;

  #pragma unroll
  for (int kk = 0; kk < 24; ++kk) {
    __builtin_amdgcn_s_barrier();               // all waves done with slot (kk+1)&1
    __builtin_amdgcn_sched_barrier(0);          // pin: nothing crosses the barrier
    if (kk < 23) {
      stageA((kk + 1) & 1, kk + 1);             // 2 ops
      loadB(b[(kk + 1) & 1], kk + 1);           // 4 ops
      VMCNT(6);                                 // retire tile kk's 6; kk+1 in flight
    } else {
      VMCNT(0);
    }

    const char* ab = smem + (kk & 1) * 8192;
    #pragma unroll
    for (int rf = 0; rf < 4; ++rf) {
      const char* rp = ab + (rf * 16 + c) * 128;
      const float4 fa = *(const float4*)(rp + ((g * 32) ^ sx));
      const float4 fb = *(const float4*)(rp + ((g * 32 + 16) ^ sx));
      uint4 pk;
      pk.x = f2bf(fa.x) | (f2bf(fa.y) << 16);
      pk.y = f2bf(fa.z) | (f2bf(fa.w) << 16);
      pk.z = f2bf(fb.x) | (f2bf(fb.y) << 16);
      pk.w = f2bf(fb.z) | (f2bf(fb.w) << 16);
      const bf16x8 afr = __builtin_bit_cast(bf16x8, pk);
      #pragma unroll
      for (int cf = 0; cf < 4; ++cf)
        acc[rf][cf] = __builtin_amdgcn_mfma_f32_16x16x32_bf16(
            afr, __builtin_bit_cast(bf16x8, b[kk & 1][cf]), acc[rf][cf], 0, 0, 0);
    }
  }

  // ---- epilogue tables (loaded after K-loop so vmcnt counting stays exact) --
  for (int i = t; i < 1024; i += 256) { wsd_s[i] = wf[1536 + i]; delta_s[i] = wf[2816 + i]; }
  base_s[t] = wf[2560 + t];
  woa_s[t] = Wo[t];
  wo2_s[t] = Wo[256 + t];
  bl_s[t] = bl[t];
  if (t < 4) csd_s[t] = wf[3840 + t];
  __syncthreads();

  // Pass 1 (col-split): per-wave partial sdiff/relu-dot over its 64 cols,
  // 16-lane shuffle reduce, per-rf. C frag (rf,cf): row = rf*16 + g*4 + j,
  // col = w*64 + cf*16 + c.   (verified R5/R9/R10)
  #pragma unroll
  for (int rf = 0; rf < 4; ++rf) {
    float psd[4][4] = {};
    float pr2[4] = {};
    #pragma unroll
    for (int cf = 0; cf < 4; ++cf) {
      const int col = w * 64 + cf * 16 + c;
      const float w0 = wsd_s[col], w1 = wsd_s[256 + col],
                  w2 = wsd_s[512 + col], w3 = wsd_s[768 + col];
      const float wo = wo2_s[col], bb2 = bl_s[col];
      #pragma unroll
      for (int j = 0; j < 4; ++j) {
        const float x = acc[rf][cf][j] + bb2;
        psd[j][0] = fmaf(x, w0, psd[j][0]);
        psd[j][1] = fmaf(x, w1, psd[j][1]);
        psd[j][2] = fmaf(x, w2, psd[j][2]);
        psd[j][3] = fmaf(x, w3, psd[j][3]);
        pr2[j] = fmaf(fmaxf(x, 0.f), wo, pr2[j]);
      }
    }
    #pragma unroll
    for (int off = 8; off; off >>= 1) {
      #pragma unroll
      for (int j = 0; j < 4; ++j) {
        #pragma unroll
        for (int h = 0; h < 4; ++h) psd[j][h] += __shfl_xor(psd[j][h], off);
        pr2[j] += __shfl_xor(pr2[j], off);
      }
    }
    if (c == 0) {
      #pragma unroll
      for (int j = 0; j < 4; ++j) {
        const int row = rf * 16 + g * 4 + j;
        #pragma unroll
        for (int h = 0; h < 4; ++h) psd_p[w * 256 + row * 4 + h] = psd[j][h];
        pr2_p[w * 64 + row] = pr2[j];
      }
    }
  }
  __syncthreads();

  // combine partials across 4 waves -> gates + r2
  if (t < 64) {
    #pragma unroll
    for (int h = 0; h < 4; ++h) {
      float sd = csd_s[h];
      #pragma unroll
      for (int ww = 0; ww < 4; ++ww) sd += psd_p[ww * 256 + t * 4 + h];
      a_s[t][h] = 1.f / (1.f + __expf(-sd));
    }
    float rr = 0.f;
    #pragma unroll
    for (int ww = 0; ww < 4; ++ww) rr += pr2_p[ww * 64 + t];
    r2_s[t] = rr;
  }
  __syncthreads();

  // Pass 2: attended reconstruction + relu-dot, 4 col-quarters x 64 rows.
  {
    const int r = t & 63, q = t >> 6;
    const float a0 = a_s[r][0], a1 = a_s[r][1], a2 = a_s[r][2], a3 = a_s[r][3];
    float p = 0.f;
    const int j0 = q * 64;
    #pragma unroll 4
    for (int j = j0; j < j0 + 64; ++j) {
      float att = base_s[j];
      att = fmaf(a0, delta_s[j], att);
      att = fmaf(a1, delta_s[256 + j], att);
      att = fmaf(a2, delta_s[512 + j], att);
      att = fmaf(a3, delta_s[768 + j], att);
      p = fmaf(fmaxf(att, 0.f), woa_s[j], p);
    }
    p2_s[q][r] = p;
  }
  __syncthreads();
  if (t < 64)
    out[m0 + t] = p2_s[0][t] + p2_s[1][t] + p2_s[2][t] + p2_s[3][t] + r2_s[t] + bo[0];
}

// ---------------------------------------------------------------------------
extern "C" void kernel_launch(void* const* d_in, const int* in_sizes, int n_in,
                              void* d_out, int out_size, void* d_ws, size_t ws_size,
                              hipStream_t stream) {
  const float* user  = (const float*)d_in[0];
  const float* query = (const float*)d_in[1];
  const float* llm   = (const float*)d_in[2];
  const float* Wu    = (const float*)d_in[3];
  const float* bu    = (const float*)d_in[4];
  const float* Wq    = (const float*)d_in[5];
  const float* bq    = (const float*)d_in[6];
  const float* Wl    = (const float*)d_in[7];
  const float* bl    = (const float*)d_in[8];
  const float* ipw   = (const float*)d_in[9];
  const float* ipb   = (const float*)d_in[10];
  const float* opw   = (const float*)d_in[11];
  const float* opb   = (const float*)d_in[12];
  const float* Wo    = (const float*)d_in[13];
  const float* bo    = (const float*)d_in[14];
  float* out = (float*)d_out;
  float* wf = (float*)d_ws;
  unsigned int* Bs4 = (unsigned int*)(wf + 4096);

  prep_a<<<64, 256, 0, stream>>>(user, query, Wu, bu, Wq, bq, wf);
  prep_w<<<96, 256, 0, stream>>>(Wl, Bs4);
  prep_b<<<128, 256, 0, stream>>>(ipw, ipb, wf);
  prep_c<<<5, 256, 0, stream>>>(ipw, ipb, opw, opb, wf);
  fused_main<<<131072 / 64, 256, 0, stream>>>(llm, bl, Wo, bo, wf, out);
}